// Round 10
// baseline (65.880 us; speedup 1.0000x reference)
//
#include <hip/hip_runtime.h>
#include <hip/hip_bf16.h>

#define N_NODES 10000
#define IN_FEAT 512
#define OUT_FEAT 512
#define N_EDGES 160000
#define KDIM 1024  // 2*IN_FEAT
#define CAP 96     // bucket capacity per node; deg ~ Poisson(16)

typedef __bf16 bf16x8 __attribute__((ext_vector_type(8)));
typedef float f32x4 __attribute__((ext_vector_type(4)));

#define AS1 __attribute__((address_space(1)))
#define AS3 __attribute__((address_space(3)))

__device__ __forceinline__ void async_copy16(void* lds, const void* g) {
    __builtin_amdgcn_global_load_lds((const AS1 unsigned int*)g,
                                     (AS3 unsigned int*)lds, 16, 0, 0);
}

__device__ __forceinline__ unsigned short f2bf(float f) {
    unsigned int u = __builtin_bit_cast(unsigned int, f);
    u += 0x7fffu + ((u >> 16) & 1u);   // RNE
    return (unsigned short)(u >> 16);
}

// ---------------- cnt zero ----------------

__global__ __launch_bounds__(256) void k_zero(int* __restrict__ cnt) {
    int i = blockIdx.x * 256 + threadIdx.x;
    if (i < N_NODES / 4) ((int4*)cnt)[i] = (int4){0, 0, 0, 0};
}

// ------- fused prep: edge bucket-scatter + w->bf16 + x->bf16 -------

#define PREP_EDGE_BLOCKS ((N_EDGES + 255) / 256)                  // 625
#define PREP_W_BLOCKS (OUT_FEAT * KDIM / 8 / 256)                 // 256
#define PREP_X_BLOCKS (N_NODES * IN_FEAT / 8 / 256)               // 2500
#define PREP_BLOCKS (PREP_EDGE_BLOCKS + PREP_W_BLOCKS + PREP_X_BLOCKS)

__device__ __forceinline__ void cvt8(const float* __restrict__ src,
                                     unsigned short* __restrict__ dst, int i) {
    const float4* sp = (const float4*)(src + (size_t)i * 8);
    float4 a = sp[0], b = sp[1];
    uint4 o;
    o.x = (unsigned)f2bf(a.x) | ((unsigned)f2bf(a.y) << 16);
    o.y = (unsigned)f2bf(a.z) | ((unsigned)f2bf(a.w) << 16);
    o.z = (unsigned)f2bf(b.x) | ((unsigned)f2bf(b.y) << 16);
    o.w = (unsigned)f2bf(b.z) | ((unsigned)f2bf(b.w) << 16);
    *(uint4*)(dst + (size_t)i * 8) = o;
}

__global__ __launch_bounds__(256) void k_prep(
    const float* __restrict__ x, const float* __restrict__ w,
    const int* __restrict__ ei, int* __restrict__ cnt,
    int* __restrict__ bucket, unsigned short* __restrict__ xb,
    unsigned short* __restrict__ wb) {
    int b = blockIdx.x;
    if (b < PREP_EDGE_BLOCKS) {
        int e = b * 256 + threadIdx.x;
        if (e < N_EDGES) {
            int s = ei[e];
            int d = ei[N_EDGES + e];
            int slot = atomicAdd(&cnt[d], 1);
            if (slot < CAP) bucket[d * CAP + slot] = s;
        }
    } else if (b < PREP_EDGE_BLOCKS + PREP_W_BLOCKS) {
        int i = (b - PREP_EDGE_BLOCKS) * 256 + threadIdx.x;
        cvt8(w, wb, i);
    } else {
        int i = (b - PREP_EDGE_BLOCKS - PREP_W_BLOCKS) * 256 + threadIdx.x;
        cvt8(x, xb, i);
    }
}

// --- aggregation: one wave per node, full-row uint4 gather, 8-deep MLP (R4) ---

__device__ __forceinline__ void accum8(float* acc, uint4 v) {
    unsigned d[4] = {v.x, v.y, v.z, v.w};
#pragma unroll
    for (int j = 0; j < 4; ++j) {
        acc[2 * j]     += __builtin_bit_cast(float, d[j] << 16);
        acc[2 * j + 1] += __builtin_bit_cast(float, d[j] & 0xffff0000u);
    }
}

__global__ __launch_bounds__(256) void k_aggregate(
    const unsigned short* __restrict__ xb, const int* __restrict__ cnt,
    const int* __restrict__ bucket, unsigned short* __restrict__ mb) {
    int wid = (blockIdx.x * 256 + threadIdx.x) >> 6;  // node
    int lane = threadIdx.x & 63;
    if (wid >= N_NODES) return;
    int deg = cnt[wid];
    int n = deg < CAP ? deg : CAP;
    const int4* brow = (const int4*)(bucket + wid * CAP);  // CAP%4==0
    const unsigned short* xrow = xb + lane * 8;
    float acc[8] = {0.f, 0.f, 0.f, 0.f, 0.f, 0.f, 0.f, 0.f};
    int e = 0;
    for (; e + 8 <= n; e += 8) {
        int4 i0 = brow[e >> 2];
        int4 i1 = brow[(e >> 2) + 1];
        uint4 v0 = *(const uint4*)(xrow + (size_t)i0.x * IN_FEAT);
        uint4 v1 = *(const uint4*)(xrow + (size_t)i0.y * IN_FEAT);
        uint4 v2 = *(const uint4*)(xrow + (size_t)i0.z * IN_FEAT);
        uint4 v3 = *(const uint4*)(xrow + (size_t)i0.w * IN_FEAT);
        uint4 v4 = *(const uint4*)(xrow + (size_t)i1.x * IN_FEAT);
        uint4 v5 = *(const uint4*)(xrow + (size_t)i1.y * IN_FEAT);
        uint4 v6 = *(const uint4*)(xrow + (size_t)i1.z * IN_FEAT);
        uint4 v7 = *(const uint4*)(xrow + (size_t)i1.w * IN_FEAT);
        accum8(acc, v0); accum8(acc, v1); accum8(acc, v2); accum8(acc, v3);
        accum8(acc, v4); accum8(acc, v5); accum8(acc, v6); accum8(acc, v7);
    }
    if (e + 4 <= n) {
        int4 i0 = brow[e >> 2];
        uint4 v0 = *(const uint4*)(xrow + (size_t)i0.x * IN_FEAT);
        uint4 v1 = *(const uint4*)(xrow + (size_t)i0.y * IN_FEAT);
        uint4 v2 = *(const uint4*)(xrow + (size_t)i0.z * IN_FEAT);
        uint4 v3 = *(const uint4*)(xrow + (size_t)i0.w * IN_FEAT);
        accum8(acc, v0); accum8(acc, v1); accum8(acc, v2); accum8(acc, v3);
        e += 4;
    }
    for (; e < n; ++e) {
        int s = bucket[wid * CAP + e];
        uint4 v = *(const uint4*)(xrow + (size_t)s * IN_FEAT);
        accum8(acc, v);
    }
    float inv = 1.0f / fmaxf((float)deg, 1.0f);
    uint4 o;
    o.x = (unsigned)f2bf(acc[0] * inv) | ((unsigned)f2bf(acc[1] * inv) << 16);
    o.y = (unsigned)f2bf(acc[2] * inv) | ((unsigned)f2bf(acc[3] * inv) << 16);
    o.z = (unsigned)f2bf(acc[4] * inv) | ((unsigned)f2bf(acc[5] * inv) << 16);
    o.w = (unsigned)f2bf(acc[6] * inv) | ((unsigned)f2bf(acc[7] * inv) << 16);
    *(uint4*)(mb + (size_t)wid * IN_FEAT + lane * 8) = o;
}

// ---- GEMM: BM=64 BN=128 BK=64, T2 swizzle + LDS dbuf prefetch + XCD remap ----
// dbuf: one vmcnt(0)+barrier per K-step at loop top; STAGE(next) issued
// before compute so loads fly under the 16 MFMAs (T3-minimum pattern).
// XCD remap: idx%8 = XCD (round-robin dispatch); mt=(idx&7)+8*(idx>>5),
// nt=(idx>>3)&3 puts the 4 n-strips of one m-tile on one XCD -> A-panel
// fetched once from HBM/L3, 3x from local L2.

#define BM 64
#define BN 128
#define BK 64
#define NSTEP (KDIM / BK)  // 16
#define MT_CNT ((N_NODES + BM - 1) / BM)  // 157

__global__ __launch_bounds__(256) void k_gemm(const unsigned short* __restrict__ xb,
                                              const unsigned short* __restrict__ mb,
                                              const unsigned short* __restrict__ wb,
                                              float* __restrict__ out) {
    __shared__ unsigned short As[2][BM * BK];  // 2 x 8 KB
    __shared__ unsigned short Bs[2][BN * BK];  // 2 x 16 KB
    const int idx = blockIdx.x;
    const int mt = (idx & 7) + 8 * (idx >> 5);
    const int nt = (idx >> 3) & 3;
    if (mt >= MT_CNT) return;
    const int m0 = mt * BM;
    const int n0 = nt * BN;

    const int tid = threadIdx.x;
    const int lane = tid & 63;
    const int w = tid >> 6;
    const int wr = w >> 1, wc = w & 1;  // 2x2 wave grid; wave tile 32x64

    // staging: issue = 8 rows x 64 cols; source col pre-swizzled (rule #21)
    const int st_sub = lane >> 3;                        // 0..7
    const int st_col = ((lane & 7) ^ st_sub) * 8;        // element col, swizzled

    f32x4 acc[2][4];
#pragma unroll
    for (int m = 0; m < 2; ++m)
#pragma unroll
        for (int n = 0; n < 4; ++n) acc[m][n] = (f32x4){0.f, 0.f, 0.f, 0.f};

    auto stage = [&](int buf, int k0) {
        const unsigned short* abase = (k0 < IN_FEAT) ? xb : mb;
        const int kc = (k0 < IN_FEAT) ? k0 : (k0 - IN_FEAT);
#pragma unroll
        for (int i = 0; i < 2; ++i) {  // A: 16 rows per wave
            int row = w * 16 + i * 8 + st_sub;
            int rg = m0 + row;
            if (rg > N_NODES - 1) rg = N_NODES - 1;  // clamp tail reads
            async_copy16(&As[buf][(w * 16 + i * 8) * BK],
                         abase + (size_t)rg * IN_FEAT + kc + st_col);
        }
#pragma unroll
        for (int i = 0; i < 4; ++i) {  // B: 32 rows per wave
            int row = w * 32 + i * 8 + st_sub;
            async_copy16(&Bs[buf][(w * 32 + i * 8) * BK],
                         wb + (size_t)(n0 + row) * KDIM + k0 + st_col);
        }
    };

    stage(0, 0);
    int cur = 0;
    for (int t = 0; t < NSTEP; ++t) {
        __syncthreads();  // vmcnt(0)+lgkmcnt(0)+s_barrier: buf[cur] ready,
                          // all reads of buf[cur^1] complete
        if (t + 1 < NSTEP) stage(cur ^ 1, (t + 1) * BK);  // flies under MFMAs

#pragma unroll
        for (int kk = 0; kk < 2; ++kk) {
            bf16x8 a[2], b[4];
            // phys 16B slot = logical ^ (row&7); row&7 == lane&7 here
            const int lslot = kk * 4 + (lane >> 4);
            const int pslot = lslot ^ (lane & 7);
#pragma unroll
            for (int m = 0; m < 2; ++m) {
                int r = wr * 32 + m * 16 + (lane & 15);
                a[m] = *(const bf16x8*)((const char*)As[cur] + r * 128 + pslot * 16);
            }
#pragma unroll
            for (int n = 0; n < 4; ++n) {
                int r = wc * 64 + n * 16 + (lane & 15);
                b[n] = *(const bf16x8*)((const char*)Bs[cur] + r * 128 + pslot * 16);
            }
#pragma unroll
            for (int m = 0; m < 2; ++m)
#pragma unroll
                for (int n = 0; n < 4; ++n)
                    acc[m][n] = __builtin_amdgcn_mfma_f32_16x16x32_bf16(
                        a[m], b[n], acc[m][n], 0, 0, 0);
        }
        cur ^= 1;
    }

    const int col_in = lane & 15;
    const int rquad = (lane >> 4) * 4;
#pragma unroll
    for (int m = 0; m < 2; ++m) {
#pragma unroll
        for (int n = 0; n < 4; ++n) {
#pragma unroll
            for (int r = 0; r < 4; ++r) {
                int mg = m0 + wr * 32 + m * 16 + rquad + r;
                int og = n0 + wc * 64 + n * 16 + col_in;
                if (mg < N_NODES) {
                    float v = acc[m][n][r];
                    out[(size_t)mg * OUT_FEAT + og] = v > 0.f ? v : 0.f;
                }
            }
        }
    }
}

// ---------------- launch ----------------

extern "C" void kernel_launch(void* const* d_in, const int* in_sizes, int n_in,
                              void* d_out, int out_size, void* d_ws, size_t ws_size,
                              hipStream_t stream) {
    const float* x = (const float*)d_in[0];
    const float* w = (const float*)d_in[1];
    const int* ei = (const int*)d_in[2];
    float* out = (float*)d_out;

    char* ws = (char*)d_ws;
    const size_t XB_OFF = 0;                                        // 10.24 MB
    const size_t MB_OFF = XB_OFF + (size_t)N_NODES * IN_FEAT * 2;   // 10.24 MB
    const size_t WB_OFF = MB_OFF + (size_t)N_NODES * IN_FEAT * 2;   // 1.05 MB
    const size_t CNT_OFF = WB_OFF + (size_t)OUT_FEAT * KDIM * 2;    // 40 KB
    const size_t BKT_OFF = CNT_OFF + (size_t)N_NODES * 4;           // 3.84 MB

    unsigned short* xb = (unsigned short*)(ws + XB_OFF);
    unsigned short* mb = (unsigned short*)(ws + MB_OFF);
    unsigned short* wb = (unsigned short*)(ws + WB_OFF);
    int* cnt = (int*)(ws + CNT_OFF);
    int* bucket = (int*)(ws + BKT_OFF);

    k_zero<<<(N_NODES / 4 + 255) / 256, 256, 0, stream>>>(cnt);
    k_prep<<<PREP_BLOCKS, 256, 0, stream>>>(x, w, ei, cnt, bucket, xb, wb);
    k_aggregate<<<(N_NODES * 64 + 255) / 256, 256, 0, stream>>>(xb, cnt, bucket, mb);
    // 640 = 20 m-groups x 32 (8 XCD x 4 n-strips); mt>=157 early-exits
    k_gemm<<<640, 256, 0, stream>>>(xb, mb, wb, out);
}

// Round 13
// 61.876 us; speedup vs baseline: 1.0647x; 1.0647x over previous
//
#include <hip/hip_runtime.h>
#include <hip/hip_bf16.h>

#define N_NODES 10000
#define IN_FEAT 512
#define OUT_FEAT 512
#define N_EDGES 160000
#define KDIM 1024  // 2*IN_FEAT
#define CAP 96     // bucket capacity per node; deg ~ Poisson(16)

typedef __bf16 bf16x8 __attribute__((ext_vector_type(8)));
typedef float f32x4 __attribute__((ext_vector_type(4)));

#define AS1 __attribute__((address_space(1)))
#define AS3 __attribute__((address_space(3)))

__device__ __forceinline__ void async_copy16(void* lds, const void* g) {
    __builtin_amdgcn_global_load_lds((const AS1 unsigned int*)g,
                                     (AS3 unsigned int*)lds, 16, 0, 0);
}

__device__ __forceinline__ unsigned short f2bf(float f) {
    unsigned int u = __builtin_bit_cast(unsigned int, f);
    u += 0x7fffu + ((u >> 16) & 1u);   // RNE
    return (unsigned short)(u >> 16);
}

// ---------------- cnt zero ----------------

__global__ __launch_bounds__(256) void k_zero(int* __restrict__ cnt) {
    int i = blockIdx.x * 256 + threadIdx.x;
    if (i < N_NODES / 4) ((int4*)cnt)[i] = (int4){0, 0, 0, 0};
}

// --- fused prep: edge bucket-scatter + w->bf16 + x->{bf16, fp8 e4m3} ---

#define PREP_EDGE_BLOCKS ((N_EDGES + 255) / 256)                  // 625
#define PREP_W_BLOCKS (OUT_FEAT * KDIM / 8 / 256)                 // 256
#define PREP_X_BLOCKS (N_NODES * IN_FEAT / 8 / 256)               // 2500
#define PREP_BLOCKS (PREP_EDGE_BLOCKS + PREP_W_BLOCKS + PREP_X_BLOCKS)

__device__ __forceinline__ void cvt8(const float* __restrict__ src,
                                     unsigned short* __restrict__ dst, int i) {
    const float4* sp = (const float4*)(src + (size_t)i * 8);
    float4 a = sp[0], b = sp[1];
    uint4 o;
    o.x = (unsigned)f2bf(a.x) | ((unsigned)f2bf(a.y) << 16);
    o.y = (unsigned)f2bf(a.z) | ((unsigned)f2bf(a.w) << 16);
    o.z = (unsigned)f2bf(b.x) | ((unsigned)f2bf(b.y) << 16);
    o.w = (unsigned)f2bf(b.z) | ((unsigned)f2bf(b.w) << 16);
    *(uint4*)(dst + (size_t)i * 8) = o;
}

__global__ __launch_bounds__(256) void k_prep(
    const float* __restrict__ x, const float* __restrict__ w,
    const int* __restrict__ ei, int* __restrict__ cnt,
    int* __restrict__ bucket, unsigned short* __restrict__ xb,
    unsigned short* __restrict__ wb, unsigned* __restrict__ xq) {
    int b = blockIdx.x;
    if (b < PREP_EDGE_BLOCKS) {
        int e = b * 256 + threadIdx.x;
        if (e < N_EDGES) {
            int s = ei[e];
            int d = ei[N_EDGES + e];
            int slot = atomicAdd(&cnt[d], 1);
            if (slot < CAP) bucket[d * CAP + slot] = s;
        }
    } else if (b < PREP_EDGE_BLOCKS + PREP_W_BLOCKS) {
        int i = (b - PREP_EDGE_BLOCKS) * 256 + threadIdx.x;
        cvt8(w, wb, i);
    } else {
        int i = (b - PREP_EDGE_BLOCKS - PREP_W_BLOCKS) * 256 + threadIdx.x;
        const float4* sp = (const float4*)(x + (size_t)i * 8);
        float4 a = sp[0], bb = sp[1];
        // bf16 copy (GEMM A operand)
        uint4 o;
        o.x = (unsigned)f2bf(a.x) | ((unsigned)f2bf(a.y) << 16);
        o.y = (unsigned)f2bf(a.z) | ((unsigned)f2bf(a.w) << 16);
        o.z = (unsigned)f2bf(bb.x) | ((unsigned)f2bf(bb.y) << 16);
        o.w = (unsigned)f2bf(bb.z) | ((unsigned)f2bf(bb.w) << 16);
        *(uint4*)(xb + (size_t)i * 8) = o;
        // fp8 e4m3 copy (aggregate gather operand), 8 floats -> 2 dwords
        unsigned q0 = __builtin_amdgcn_cvt_pk_fp8_f32(a.x, a.y, 0, false);
        q0 = __builtin_amdgcn_cvt_pk_fp8_f32(a.z, a.w, q0, true);
        unsigned q1 = __builtin_amdgcn_cvt_pk_fp8_f32(bb.x, bb.y, 0, false);
        q1 = __builtin_amdgcn_cvt_pk_fp8_f32(bb.z, bb.w, q1, true);
        ((uint2*)xq)[i] = (uint2){q0, q1};
    }
}

// --- aggregation: one wave per node, fp8 uint2 gather, 16-deep MLP ---
// row = 512 fp8 = 512 B; lane owns 8 bytes. 16 outstanding loads = 128 B/lane
// in flight. HW v_cvt_f32_fp8 dequant (selector must be LITERAL -> unrolled).

__device__ __forceinline__ void accq(float* acc, uint2 v) {
    acc[0] += __builtin_amdgcn_cvt_f32_fp8(v.x, 0);
    acc[1] += __builtin_amdgcn_cvt_f32_fp8(v.x, 1);
    acc[2] += __builtin_amdgcn_cvt_f32_fp8(v.x, 2);
    acc[3] += __builtin_amdgcn_cvt_f32_fp8(v.x, 3);
    acc[4] += __builtin_amdgcn_cvt_f32_fp8(v.y, 0);
    acc[5] += __builtin_amdgcn_cvt_f32_fp8(v.y, 1);
    acc[6] += __builtin_amdgcn_cvt_f32_fp8(v.y, 2);
    acc[7] += __builtin_amdgcn_cvt_f32_fp8(v.y, 3);
}

__global__ __launch_bounds__(256) void k_aggregate(
    const unsigned* __restrict__ xq, const int* __restrict__ cnt,
    const int* __restrict__ bucket, unsigned short* __restrict__ mb) {
    int wid = (blockIdx.x * 256 + threadIdx.x) >> 6;  // node
    int lane = threadIdx.x & 63;
    if (wid >= N_NODES) return;
    int deg = cnt[wid];
    int n = deg < CAP ? deg : CAP;
    const int4* brow = (const int4*)(bucket + wid * CAP);  // CAP%4==0
    const uint2* xrow = (const uint2*)xq + lane;  // 8B per lane, row stride 64
    float acc[8] = {0.f, 0.f, 0.f, 0.f, 0.f, 0.f, 0.f, 0.f};
    int e = 0;
    for (; e + 16 <= n; e += 16) {
        int4 i0 = brow[(e >> 2) + 0];
        int4 i1 = brow[(e >> 2) + 1];
        int4 i2 = brow[(e >> 2) + 2];
        int4 i3 = brow[(e >> 2) + 3];
        uint2 v0 = xrow[(size_t)i0.x * 64];
        uint2 v1 = xrow[(size_t)i0.y * 64];
        uint2 v2 = xrow[(size_t)i0.z * 64];
        uint2 v3 = xrow[(size_t)i0.w * 64];
        uint2 v4 = xrow[(size_t)i1.x * 64];
        uint2 v5 = xrow[(size_t)i1.y * 64];
        uint2 v6 = xrow[(size_t)i1.z * 64];
        uint2 v7 = xrow[(size_t)i1.w * 64];
        uint2 v8 = xrow[(size_t)i2.x * 64];
        uint2 v9 = xrow[(size_t)i2.y * 64];
        uint2 va = xrow[(size_t)i2.z * 64];
        uint2 vb = xrow[(size_t)i2.w * 64];
        uint2 vc = xrow[(size_t)i3.x * 64];
        uint2 vd = xrow[(size_t)i3.y * 64];
        uint2 ve = xrow[(size_t)i3.z * 64];
        uint2 vf = xrow[(size_t)i3.w * 64];
        accq(acc, v0); accq(acc, v1); accq(acc, v2); accq(acc, v3);
        accq(acc, v4); accq(acc, v5); accq(acc, v6); accq(acc, v7);
        accq(acc, v8); accq(acc, v9); accq(acc, va); accq(acc, vb);
        accq(acc, vc); accq(acc, vd); accq(acc, ve); accq(acc, vf);
    }
    if (e + 8 <= n) {
        int4 i0 = brow[(e >> 2) + 0];
        int4 i1 = brow[(e >> 2) + 1];
        uint2 v0 = xrow[(size_t)i0.x * 64];
        uint2 v1 = xrow[(size_t)i0.y * 64];
        uint2 v2 = xrow[(size_t)i0.z * 64];
        uint2 v3 = xrow[(size_t)i0.w * 64];
        uint2 v4 = xrow[(size_t)i1.x * 64];
        uint2 v5 = xrow[(size_t)i1.y * 64];
        uint2 v6 = xrow[(size_t)i1.z * 64];
        uint2 v7 = xrow[(size_t)i1.w * 64];
        accq(acc, v0); accq(acc, v1); accq(acc, v2); accq(acc, v3);
        accq(acc, v4); accq(acc, v5); accq(acc, v6); accq(acc, v7);
        e += 8;
    }
    if (e + 4 <= n) {
        int4 i0 = brow[e >> 2];
        uint2 v0 = xrow[(size_t)i0.x * 64];
        uint2 v1 = xrow[(size_t)i0.y * 64];
        uint2 v2 = xrow[(size_t)i0.z * 64];
        uint2 v3 = xrow[(size_t)i0.w * 64];
        accq(acc, v0); accq(acc, v1); accq(acc, v2); accq(acc, v3);
        e += 4;
    }
    for (; e < n; ++e) {
        uint2 v = xrow[(size_t)bucket[wid * CAP + e] * 64];
        accq(acc, v);
    }
    float inv = 1.0f / fmaxf((float)deg, 1.0f);
    uint4 o;
    o.x = (unsigned)f2bf(acc[0] * inv) | ((unsigned)f2bf(acc[1] * inv) << 16);
    o.y = (unsigned)f2bf(acc[2] * inv) | ((unsigned)f2bf(acc[3] * inv) << 16);
    o.z = (unsigned)f2bf(acc[4] * inv) | ((unsigned)f2bf(acc[5] * inv) << 16);
    o.w = (unsigned)f2bf(acc[6] * inv) | ((unsigned)f2bf(acc[7] * inv) << 16);
    *(uint4*)(mb + (size_t)wid * IN_FEAT + lane * 8) = o;
}

// ---- GEMM: BM=64 BN=128 BK=64, T2 swizzle, single buffer (R9, proven) ----

#define BM 64
#define BN 128
#define BK 64

__global__ __launch_bounds__(256) void k_gemm(const unsigned short* __restrict__ xb,
                                              const unsigned short* __restrict__ mb,
                                              const unsigned short* __restrict__ wb,
                                              float* __restrict__ out) {
    __shared__ unsigned short As[BM * BK];  // 8 KB
    __shared__ unsigned short Bs[BN * BK];  // 16 KB
    const int tid = threadIdx.x;
    const int lane = tid & 63;
    const int w = tid >> 6;
    const int m0 = blockIdx.x * BM;
    const int n0 = blockIdx.y * BN;

    const int wr = w >> 1, wc = w & 1;  // 2x2 wave grid; wave tile 32x64

    const int st_sub = lane >> 3;                        // 0..7
    const int st_col = ((lane & 7) ^ st_sub) * 8;        // swizzled source col

    f32x4 acc[2][4];
#pragma unroll
    for (int m = 0; m < 2; ++m)
#pragma unroll
        for (int n = 0; n < 4; ++n) acc[m][n] = (f32x4){0.f, 0.f, 0.f, 0.f};

    for (int k0 = 0; k0 < KDIM; k0 += BK) {
        const unsigned short* abase = (k0 < IN_FEAT) ? xb : mb;
        const int kc = (k0 < IN_FEAT) ? k0 : (k0 - IN_FEAT);
#pragma unroll
        for (int i = 0; i < 2; ++i) {  // A: 16 rows per wave
            int row = w * 16 + i * 8 + st_sub;
            int rg = m0 + row;
            if (rg > N_NODES - 1) rg = N_NODES - 1;  // clamp tail reads
            async_copy16(&As[(w * 16 + i * 8) * BK],
                         abase + (size_t)rg * IN_FEAT + kc + st_col);
        }
#pragma unroll
        for (int i = 0; i < 4; ++i) {  // B: 32 rows per wave
            int row = w * 32 + i * 8 + st_sub;
            async_copy16(&Bs[(w * 32 + i * 8) * BK],
                         wb + (size_t)(n0 + row) * KDIM + k0 + st_col);
        }
        __syncthreads();

#pragma unroll
        for (int kk = 0; kk < 2; ++kk) {
            bf16x8 a[2], b[4];
            const int lslot = kk * 4 + (lane >> 4);
            const int pslot = lslot ^ (lane & 7);
#pragma unroll
            for (int m = 0; m < 2; ++m) {
                int r = wr * 32 + m * 16 + (lane & 15);
                a[m] = *(const bf16x8*)((const char*)As + r * 128 + pslot * 16);
            }
#pragma unroll
            for (int n = 0; n < 4; ++n) {
                int r = wc * 64 + n * 16 + (lane & 15);
                b[n] = *(const bf16x8*)((const char*)Bs + r * 128 + pslot * 16);
            }
#pragma unroll
            for (int m = 0; m < 2; ++m)
#pragma unroll
                for (int n = 0; n < 4; ++n)
                    acc[m][n] = __builtin_amdgcn_mfma_f32_16x16x32_bf16(
                        a[m], b[n], acc[m][n], 0, 0, 0);
        }
        __syncthreads();
    }

    const int col_in = lane & 15;
    const int rquad = (lane >> 4) * 4;
#pragma unroll
    for (int m = 0; m < 2; ++m) {
#pragma unroll
        for (int n = 0; n < 4; ++n) {
#pragma unroll
            for (int r = 0; r < 4; ++r) {
                int mg = m0 + wr * 32 + m * 16 + rquad + r;
                int og = n0 + wc * 64 + n * 16 + col_in;
                if (mg < N_NODES) {
                    float v = acc[m][n][r];
                    out[(size_t)mg * OUT_FEAT + og] = v > 0.f ? v : 0.f;
                }
            }
        }
    }
}

// ---------------- launch ----------------

extern "C" void kernel_launch(void* const* d_in, const int* in_sizes, int n_in,
                              void* d_out, int out_size, void* d_ws, size_t ws_size,
                              hipStream_t stream) {
    const float* x = (const float*)d_in[0];
    const float* w = (const float*)d_in[1];
    const int* ei = (const int*)d_in[2];
    float* out = (float*)d_out;

    char* ws = (char*)d_ws;
    const size_t XB_OFF = 0;                                        // 10.24 MB
    const size_t MB_OFF = XB_OFF + (size_t)N_NODES * IN_FEAT * 2;   // 10.24 MB
    const size_t WB_OFF = MB_OFF + (size_t)N_NODES * IN_FEAT * 2;   // 1.05 MB
    const size_t CNT_OFF = WB_OFF + (size_t)OUT_FEAT * KDIM * 2;    // 40 KB
    const size_t BKT_OFF = CNT_OFF + (size_t)N_NODES * 4;           // 3.84 MB
    const size_t XQ_OFF = BKT_OFF + (size_t)N_NODES * CAP * 4;      // 5.12 MB

    unsigned short* xb = (unsigned short*)(ws + XB_OFF);
    unsigned short* mb = (unsigned short*)(ws + MB_OFF);
    unsigned short* wb = (unsigned short*)(ws + WB_OFF);
    int* cnt = (int*)(ws + CNT_OFF);
    int* bucket = (int*)(ws + BKT_OFF);
    unsigned* xq = (unsigned*)(ws + XQ_OFF);

    k_zero<<<(N_NODES / 4 + 255) / 256, 256, 0, stream>>>(cnt);
    k_prep<<<PREP_BLOCKS, 256, 0, stream>>>(x, w, ei, cnt, bucket, xb, wb, xq);
    k_aggregate<<<(N_NODES * 64 + 255) / 256, 256, 0, stream>>>(xq, cnt, bucket, mb);
    dim3 ggrid((N_NODES + BM - 1) / BM, OUT_FEAT / BN);
    k_gemm<<<ggrid, 256, 0, stream>>>(xb, mb, wb, out);
}